// Round 1
// baseline (226.493 us; speedup 1.0000x reference)
//
#include <hip/hip_runtime.h>
#include <stdint.h>

#define T_SEQ 1024
#define C_DIM 1024
#define NH 16
#define DH 64

typedef __attribute__((ext_vector_type(8))) __bf16 bf16x8;
typedef __attribute__((ext_vector_type(4))) float f32x4;

__device__ __forceinline__ uint16_t f2bf(float f) {
    union { float f; uint32_t u; } v; v.f = f;
    uint32_t u = v.u;
    return (uint16_t)((u + 0x7FFFu + ((u >> 16) & 1u)) >> 16);
}

// ---------- cast x f32 -> bf16 (vectorized) ----------
__global__ void k_cast(const float* __restrict__ in, uint16_t* __restrict__ out, int n4) {
    int i = blockIdx.x * blockDim.x + threadIdx.x;
    int st = gridDim.x * blockDim.x;
    for (; i < n4; i += st) {
        float4 v = reinterpret_cast<const float4*>(in)[i];
        ushort4 o;
        o.x = f2bf(v.x); o.y = f2bf(v.y); o.z = f2bf(v.z); o.w = f2bf(v.w);
        reinterpret_cast<ushort4*>(out)[i] = o;
    }
}

// ---------- transpose + cast weight: W[k][n] f32 -> Wt[n][k] bf16 ----------
__global__ void k_transpose(const float* __restrict__ in, uint16_t* __restrict__ out) {
    __shared__ float tile[32][33];
    int bx = blockIdx.x * 32;  // n block
    int by = blockIdx.y * 32;  // k block
    int tx = threadIdx.x, ty = threadIdx.y;
#pragma unroll
    for (int i = 0; i < 4; i++)
        tile[ty + i * 8][tx] = in[(size_t)(by + ty + i * 8) * C_DIM + bx + tx];
    __syncthreads();
#pragma unroll
    for (int i = 0; i < 4; i++)
        out[(size_t)(bx + ty + i * 8) * C_DIM + by + tx] = f2bf(tile[tx][ty + i * 8]);
}

// ---------- bf16 MFMA GEMM: C[M=4096][1024] = A[4096][1024] * Bt[n][k]^T + bias ----------
// MODE 0: bf16 row-major out; MODE 1: bf16 out stored as Vt[b][h][d][t]; MODE 2: f32 row-major out
template <int MODE>
__global__ __launch_bounds__(256) void k_gemm(const uint16_t* __restrict__ A,
                                              const uint16_t* __restrict__ Bt,
                                              const float* __restrict__ bias,
                                              void* __restrict__ Out) {
    __shared__ uint16_t lA[128 * 32];
    __shared__ uint16_t lB[128 * 32];
    const int bm = blockIdx.x * 128;
    const int bn = blockIdx.y * 128;
    const int tid = threadIdx.x;
    const int lane = tid & 63;
    const int w = tid >> 6;
    const int wm = (w >> 1) * 64;
    const int wn = (w & 1) * 64;
    const int srow = tid >> 2;
    const int scol = (tid & 3) * 8;

    f32x4 acc[4][4] = {};

    for (int kt = 0; kt < C_DIM; kt += 32) {
#pragma unroll
        for (int p = 0; p < 2; p++) {
            const uint16_t* ga = A + (size_t)(bm + p * 64 + srow) * C_DIM + kt + scol;
            const uint16_t* gb = Bt + (size_t)(bn + p * 64 + srow) * C_DIM + kt + scol;
            __builtin_amdgcn_global_load_lds(
                (const __attribute__((address_space(1))) void*)ga,
                (__attribute__((address_space(3))) void*)((char*)lA + p * 4096 + w * 1024),
                16, 0, 0);
            __builtin_amdgcn_global_load_lds(
                (const __attribute__((address_space(1))) void*)gb,
                (__attribute__((address_space(3))) void*)((char*)lB + p * 4096 + w * 1024),
                16, 0, 0);
        }
        __syncthreads();
        const int ko = (lane >> 4) * 8;
        const int rr = lane & 15;
        bf16x8 af[4], bfr[4];
#pragma unroll
        for (int i = 0; i < 4; i++) {
            af[i]  = *reinterpret_cast<const bf16x8*>(&lA[(wm + i * 16 + rr) * 32 + ko]);
            bfr[i] = *reinterpret_cast<const bf16x8*>(&lB[(wn + i * 16 + rr) * 32 + ko]);
        }
#pragma unroll
        for (int mi = 0; mi < 4; mi++)
#pragma unroll
            for (int ni = 0; ni < 4; ni++)
                acc[mi][ni] = __builtin_amdgcn_mfma_f32_16x16x32_bf16(af[mi], bfr[ni], acc[mi][ni], 0, 0, 0);
        __syncthreads();
    }

    const int r0 = (lane >> 4) * 4;
    const int cc = lane & 15;
#pragma unroll
    for (int ni = 0; ni < 4; ni++) {
        const int col = bn + wn + ni * 16 + cc;
        const float bv = bias[col];
#pragma unroll
        for (int mi = 0; mi < 4; mi++) {
#pragma unroll
            for (int jj = 0; jj < 4; jj++) {
                const int row = bm + wm + mi * 16 + r0 + jj;
                float v = acc[mi][ni][jj] + bv;
                if (MODE == 2) {
                    reinterpret_cast<float*>(Out)[(size_t)row * C_DIM + col] = v;
                } else if (MODE == 0) {
                    reinterpret_cast<uint16_t*>(Out)[(size_t)row * C_DIM + col] = f2bf(v);
                } else {
                    const int b = row >> 10, t = row & 1023;
                    const int h = col >> 6, d = col & 63;
                    reinterpret_cast<uint16_t*>(Out)[((size_t)((b * NH + h) * DH + d) << 10) + t] = f2bf(v);
                }
            }
        }
    }
}

// ---------- flash attention with inverted-tril mask ----------
// Q,K: [4096][1024] bf16 (cols = h*64+d). Vt: [b][h][d][t] bf16. Ob: [4096][1024] bf16.
__global__ __launch_bounds__(64) void k_attn(const uint16_t* __restrict__ Q,
                                             const uint16_t* __restrict__ Kb,
                                             const uint16_t* __restrict__ Vt,
                                             uint16_t* __restrict__ Ob) {
    __shared__ uint16_t lp[16 * 32];
    const int lane = threadIdx.x;
    const int bh = blockIdx.y;
    const int bb = bh >> 4, h = bh & 15;
    const int q0 = blockIdx.x * 16;
    const int rr = lane & 15;
    const int ko = (lane >> 4) * 8;
    const int r0 = (lane >> 4) * 4;

    const uint16_t* qp = Q + (size_t)(bb * T_SEQ + q0 + rr) * C_DIM + h * DH + ko;
    bf16x8 aq0 = *reinterpret_cast<const bf16x8*>(qp);
    bf16x8 aq1 = *reinterpret_cast<const bf16x8*>(qp + 32);

    const uint16_t* kbase = Kb + (size_t)(bb * T_SEQ) * C_DIM + h * DH;
    const uint16_t* vbase = Vt + (size_t)bh * DH * T_SEQ;

    f32x4 o[4] = {};
    float m[4], l[4];
#pragma unroll
    for (int j = 0; j < 4; j++) { m[j] = -INFINITY; l[j] = 0.f; }

    for (int s0 = 0; s0 < T_SEQ; s0 += 32) {
        f32x4 sc[2];
#pragma unroll
        for (int hf = 0; hf < 2; hf++) {
            const uint16_t* kp = kbase + (size_t)(s0 + hf * 16 + rr) * C_DIM + ko;
            bf16x8 bk0 = *reinterpret_cast<const bf16x8*>(kp);
            bf16x8 bk1 = *reinterpret_cast<const bf16x8*>(kp + 32);
            f32x4 t = {};
            t = __builtin_amdgcn_mfma_f32_16x16x32_bf16(aq0, bk0, t, 0, 0, 0);
            t = __builtin_amdgcn_mfma_f32_16x16x32_bf16(aq1, bk1, t, 0, 0, 0);
            sc[hf] = t;
        }
        // scale + faithful mask: -1e9 where s <= t (tril incl. diagonal)
#pragma unroll
        for (int hf = 0; hf < 2; hf++)
#pragma unroll
            for (int j = 0; j < 4; j++) {
                float v = sc[hf][j] * 0.125f;
                int tg = q0 + r0 + j;
                int sg = s0 + hf * 16 + rr;
                if (sg <= tg) v -= 1e9f;
                sc[hf][j] = v;
            }
        // online softmax: row max over 32 cols (16 lanes x 2 halves)
        float mt[4];
#pragma unroll
        for (int j = 0; j < 4; j++) mt[j] = fmaxf(sc[0][j], sc[1][j]);
#pragma unroll
        for (int x = 1; x < 16; x <<= 1)
#pragma unroll
            for (int j = 0; j < 4; j++) mt[j] = fmaxf(mt[j], __shfl_xor(mt[j], x));
        float esc[4];
#pragma unroll
        for (int j = 0; j < 4; j++) {
            float mn = fmaxf(m[j], mt[j]);
            esc[j] = __expf(m[j] - mn);
            m[j] = mn;
        }
        float rs[4];
#pragma unroll
        for (int j = 0; j < 4; j++) {
            sc[0][j] = __expf(sc[0][j] - m[j]);
            sc[1][j] = __expf(sc[1][j] - m[j]);
            rs[j] = sc[0][j] + sc[1][j];
        }
#pragma unroll
        for (int x = 1; x < 16; x <<= 1)
#pragma unroll
            for (int j = 0; j < 4; j++) rs[j] += __shfl_xor(rs[j], x);
#pragma unroll
        for (int j = 0; j < 4; j++) l[j] = l[j] * esc[j] + rs[j];
#pragma unroll
        for (int ni = 0; ni < 4; ni++)
#pragma unroll
            for (int j = 0; j < 4; j++) o[ni][j] *= esc[j];
        // P -> LDS (bf16), D-layout write
#pragma unroll
        for (int hf = 0; hf < 2; hf++)
#pragma unroll
            for (int j = 0; j < 4; j++)
                lp[(r0 + j) * 32 + hf * 16 + rr] = f2bf(sc[hf][j]);
        __syncthreads();
        // A-layout read
        bf16x8 pa = *reinterpret_cast<const bf16x8*>(&lp[rr * 32 + ko]);
#pragma unroll
        for (int ni = 0; ni < 4; ni++) {
            const uint16_t* vp = vbase + (size_t)(ni * 16 + rr) * T_SEQ + s0 + ko;
            bf16x8 bv = *reinterpret_cast<const bf16x8*>(vp);
            o[ni] = __builtin_amdgcn_mfma_f32_16x16x32_bf16(pa, bv, o[ni], 0, 0, 0);
        }
        __syncthreads();
    }
#pragma unroll
    for (int ni = 0; ni < 4; ni++)
#pragma unroll
        for (int j = 0; j < 4; j++) {
            int tg = q0 + r0 + j;
            int d = ni * 16 + rr;
            Ob[(size_t)(bb * T_SEQ + tg) * C_DIM + h * DH + d] = f2bf(o[ni][j] / l[j]);
        }
}

extern "C" void kernel_launch(void* const* d_in, const int* in_sizes, int n_in,
                              void* d_out, int out_size, void* d_ws, size_t ws_size,
                              hipStream_t stream) {
    const float* x  = (const float*)d_in[0];
    const float* Wq = (const float*)d_in[1];
    const float* bq = (const float*)d_in[2];
    const float* Wk = (const float*)d_in[3];
    const float* bk = (const float*)d_in[4];
    const float* Wv = (const float*)d_in[5];
    const float* bv = (const float*)d_in[6];
    const float* Wo = (const float*)d_in[7];
    const float* bo = (const float*)d_in[8];
    float* out = (float*)d_out;

    char* ws = (char*)d_ws;
    uint16_t* xb  = (uint16_t*)(ws);
    uint16_t* wqt = (uint16_t*)(ws + (8u  << 20));
    uint16_t* wkt = (uint16_t*)(ws + (10u << 20));
    uint16_t* wvt = (uint16_t*)(ws + (12u << 20));
    uint16_t* wot = (uint16_t*)(ws + (14u << 20));
    uint16_t* qb  = (uint16_t*)(ws + (16u << 20));
    uint16_t* kb  = (uint16_t*)(ws + (24u << 20));
    uint16_t* vt  = (uint16_t*)(ws + (32u << 20));
    uint16_t* ab  = qb;  // attention output aliases qb: each attn block reads only its own q rows

    k_cast<<<2048, 256, 0, stream>>>(x, xb, (4096 * 1024) / 4);
    dim3 tg(32, 32), tb(32, 8);
    k_transpose<<<tg, tb, 0, stream>>>(Wq, wqt);
    k_transpose<<<tg, tb, 0, stream>>>(Wk, wkt);
    k_transpose<<<tg, tb, 0, stream>>>(Wv, wvt);
    k_transpose<<<tg, tb, 0, stream>>>(Wo, wot);

    dim3 gg(32, 8);
    k_gemm<0><<<gg, 256, 0, stream>>>(xb, wqt, bq, qb);
    k_gemm<0><<<gg, 256, 0, stream>>>(xb, wkt, bk, kb);
    k_gemm<1><<<gg, 256, 0, stream>>>(xb, wvt, bv, vt);
    k_attn<<<dim3(64, 64), 64, 0, stream>>>(qb, kb, vt, ab);
    k_gemm<2><<<gg, 256, 0, stream>>>(ab, wot, bo, out);
}

// Round 2
// 194.090 us; speedup vs baseline: 1.1669x; 1.1669x over previous
//
#include <hip/hip_runtime.h>
#include <hip/hip_bf16.h>
#include <stdint.h>

#define T_SEQ 1024
#define C_DIM 1024
#define NH 16
#define DH 64

typedef __attribute__((ext_vector_type(8))) __bf16 bf16x8;
typedef __attribute__((ext_vector_type(4))) float f32x4;

__device__ __forceinline__ uint16_t f2bf(float f) {
    union { float f; uint32_t u; } v; v.f = f;
    uint32_t u = v.u;
    return (uint16_t)((u + 0x7FFFu + ((u >> 16) & 1u)) >> 16);
}

// ---------- cast x f32 -> bf16 (vectorized) ----------
__global__ void k_cast(const float* __restrict__ in, uint16_t* __restrict__ out, int n4) {
    int i = blockIdx.x * blockDim.x + threadIdx.x;
    int st = gridDim.x * blockDim.x;
    for (; i < n4; i += st) {
        float4 v = reinterpret_cast<const float4*>(in)[i];
        ushort4 o;
        o.x = f2bf(v.x); o.y = f2bf(v.y); o.z = f2bf(v.z); o.w = f2bf(v.w);
        reinterpret_cast<ushort4*>(out)[i] = o;
    }
}

// ---------- transpose + cast weight: W[k][n] f32 -> Wt[n][k] bf16 ----------
__global__ void k_transpose(const float* __restrict__ in, uint16_t* __restrict__ out) {
    __shared__ float tile[32][33];
    int bx = blockIdx.x * 32;  // n block
    int by = blockIdx.y * 32;  // k block
    int tx = threadIdx.x, ty = threadIdx.y;
#pragma unroll
    for (int i = 0; i < 4; i++)
        tile[ty + i * 8][tx] = in[(size_t)(by + ty + i * 8) * C_DIM + bx + tx];
    __syncthreads();
#pragma unroll
    for (int i = 0; i < 4; i++)
        out[(size_t)(bx + ty + i * 8) * C_DIM + by + tx] = f2bf(tile[tx][ty + i * 8]);
}

// ---------- fused QKV GEMM: [4096][1024] x [3072][1024]^T ----------
// cols 0-1023 -> Q (bf16 rowmajor), 1024-2047 -> K (bf16 rowmajor),
// 2048-3071 -> V stored transposed as Vt[b][h][d][t] bf16.
__global__ __launch_bounds__(256) void k_gemm_qkv(const uint16_t* __restrict__ A,
                                                  const uint16_t* __restrict__ Bt,
                                                  const float* __restrict__ bq,
                                                  const float* __restrict__ bk,
                                                  const float* __restrict__ bv,
                                                  uint16_t* __restrict__ qb,
                                                  uint16_t* __restrict__ kb,
                                                  uint16_t* __restrict__ vt) {
    __shared__ uint16_t lA[128 * 32];
    __shared__ uint16_t lB[128 * 32];
    const int bm = blockIdx.x * 128;
    const int bn = blockIdx.y * 128;
    const int tid = threadIdx.x;
    const int lane = tid & 63;
    const int w = tid >> 6;
    const int wm = (w >> 1) * 64;
    const int wn = (w & 1) * 64;
    const int srow = tid >> 2;
    const int scol = (tid & 3) * 8;

    f32x4 acc[4][4] = {};

    for (int kt = 0; kt < C_DIM; kt += 32) {
#pragma unroll
        for (int p = 0; p < 2; p++) {
            const uint16_t* ga = A + (size_t)(bm + p * 64 + srow) * C_DIM + kt + scol;
            const uint16_t* gb = Bt + (size_t)(bn + p * 64 + srow) * C_DIM + kt + scol;
            __builtin_amdgcn_global_load_lds(
                (const __attribute__((address_space(1))) void*)ga,
                (__attribute__((address_space(3))) void*)((char*)lA + p * 4096 + w * 1024),
                16, 0, 0);
            __builtin_amdgcn_global_load_lds(
                (const __attribute__((address_space(1))) void*)gb,
                (__attribute__((address_space(3))) void*)((char*)lB + p * 4096 + w * 1024),
                16, 0, 0);
        }
        __syncthreads();
        const int ko = (lane >> 4) * 8;
        const int rr = lane & 15;
        bf16x8 af[4], bfr[4];
#pragma unroll
        for (int i = 0; i < 4; i++) {
            af[i]  = *reinterpret_cast<const bf16x8*>(&lA[(wm + i * 16 + rr) * 32 + ko]);
            bfr[i] = *reinterpret_cast<const bf16x8*>(&lB[(wn + i * 16 + rr) * 32 + ko]);
        }
#pragma unroll
        for (int mi = 0; mi < 4; mi++)
#pragma unroll
            for (int ni = 0; ni < 4; ni++)
                acc[mi][ni] = __builtin_amdgcn_mfma_f32_16x16x32_bf16(af[mi], bfr[ni], acc[mi][ni], 0, 0, 0);
        __syncthreads();
    }

    const float* bias; uint16_t* outp; int coff, vmode;
    if (bn < 1024)      { bias = bq; outp = qb; coff = 0;    vmode = 0; }
    else if (bn < 2048) { bias = bk; outp = kb; coff = 1024; vmode = 0; }
    else                { bias = bv; outp = vt; coff = 2048; vmode = 1; }

    const int r0 = (lane >> 4) * 4;
    const int cc = lane & 15;
#pragma unroll
    for (int ni = 0; ni < 4; ni++) {
        const int colg = bn + wn + ni * 16 + cc;
        const int col = colg - coff;
        const float bvv = bias[col];
#pragma unroll
        for (int mi = 0; mi < 4; mi++) {
#pragma unroll
            for (int jj = 0; jj < 4; jj++) {
                const int row = bm + wm + mi * 16 + r0 + jj;
                float v = acc[mi][ni][jj] + bvv;
                if (vmode == 0) {
                    outp[(size_t)row * C_DIM + col] = f2bf(v);
                } else {
                    const int b = row >> 10, t = row & 1023;
                    const int h = col >> 6, d = col & 63;
                    outp[((size_t)((b * NH + h) * DH + d) << 10) + t] = f2bf(v);
                }
            }
        }
    }
}

// ---------- output-proj GEMM: f32 out ----------
__global__ __launch_bounds__(256) void k_gemm_o(const uint16_t* __restrict__ A,
                                                const uint16_t* __restrict__ Bt,
                                                const float* __restrict__ bias,
                                                float* __restrict__ Out) {
    __shared__ uint16_t lA[128 * 32];
    __shared__ uint16_t lB[128 * 32];
    const int bm = blockIdx.x * 128;
    const int bn = blockIdx.y * 128;
    const int tid = threadIdx.x;
    const int lane = tid & 63;
    const int w = tid >> 6;
    const int wm = (w >> 1) * 64;
    const int wn = (w & 1) * 64;
    const int srow = tid >> 2;
    const int scol = (tid & 3) * 8;

    f32x4 acc[4][4] = {};

    for (int kt = 0; kt < C_DIM; kt += 32) {
#pragma unroll
        for (int p = 0; p < 2; p++) {
            const uint16_t* ga = A + (size_t)(bm + p * 64 + srow) * C_DIM + kt + scol;
            const uint16_t* gb = Bt + (size_t)(bn + p * 64 + srow) * C_DIM + kt + scol;
            __builtin_amdgcn_global_load_lds(
                (const __attribute__((address_space(1))) void*)ga,
                (__attribute__((address_space(3))) void*)((char*)lA + p * 4096 + w * 1024),
                16, 0, 0);
            __builtin_amdgcn_global_load_lds(
                (const __attribute__((address_space(1))) void*)gb,
                (__attribute__((address_space(3))) void*)((char*)lB + p * 4096 + w * 1024),
                16, 0, 0);
        }
        __syncthreads();
        const int ko = (lane >> 4) * 8;
        const int rr = lane & 15;
        bf16x8 af[4], bfr[4];
#pragma unroll
        for (int i = 0; i < 4; i++) {
            af[i]  = *reinterpret_cast<const bf16x8*>(&lA[(wm + i * 16 + rr) * 32 + ko]);
            bfr[i] = *reinterpret_cast<const bf16x8*>(&lB[(wn + i * 16 + rr) * 32 + ko]);
        }
#pragma unroll
        for (int mi = 0; mi < 4; mi++)
#pragma unroll
            for (int ni = 0; ni < 4; ni++)
                acc[mi][ni] = __builtin_amdgcn_mfma_f32_16x16x32_bf16(af[mi], bfr[ni], acc[mi][ni], 0, 0, 0);
        __syncthreads();
    }

    const int r0 = (lane >> 4) * 4;
    const int cc = lane & 15;
#pragma unroll
    for (int ni = 0; ni < 4; ni++) {
        const int col = bn + wn + ni * 16 + cc;
        const float bvv = bias[col];
#pragma unroll
        for (int mi = 0; mi < 4; mi++)
#pragma unroll
            for (int jj = 0; jj < 4; jj++) {
                const int row = bm + wm + mi * 16 + r0 + jj;
                Out[(size_t)row * C_DIM + col] = acc[mi][ni][jj] + bvv;
            }
    }
}

// ---------- flash attention, swapped-QK^T, 64-col KV steps ----------
// Q,K: [4096][1024] bf16. Vt: [b][h][d][t] bf16. Ob: [4096][1024] bf16.
// Per wave: 16 q-rows. S computed as mfma(K,Q) -> D[k][q], col=lane&15=q.
__global__ __launch_bounds__(64, 4) void k_attn(const uint16_t* __restrict__ Q,
                                                const uint16_t* __restrict__ Kb,
                                                const uint16_t* __restrict__ Vt,
                                                uint16_t* __restrict__ Ob) {
    __shared__ uint16_t lp[16 * 72];   // P tile, stride 72 (144B rows: 16B-aligned, low conflict)
    const int lane = threadIdx.x;
    // XCD-aware bijective swizzle: 8 heads' K/V (2MB) pinned per XCD L2
    const int id = blockIdx.x;
    const int sw = (id & 7) * 512 + (id >> 3);
    const int q0 = (sw & 63) * 16;
    const int bh = sw >> 6;
    const int bb = bh >> 4, h = bh & 15;
    const int qq = lane & 15;          // q-row (as MFMA col) / also k-row for A-frag loads
    const int g  = lane >> 4;
    const int ko = g * 8;
    const int r0 = g * 4;
    const int qg = q0 + qq;

    // Q as B-fragment: col=qq, k-dim d=ko..ko+7 (+32)
    const uint16_t* qp = Q + (size_t)(bb * T_SEQ + qg) * C_DIM + h * DH + ko;
    bf16x8 bq0 = *reinterpret_cast<const bf16x8*>(qp);
    bf16x8 bq1 = *reinterpret_cast<const bf16x8*>(qp + 32);

    const uint16_t* kbase = Kb + (size_t)(bb * T_SEQ) * C_DIM + h * DH;
    const uint16_t* vbase = Vt + (size_t)bh * DH * T_SEQ;

    f32x4 o[4] = {};
    float m = -INFINITY, l = 0.f;      // per q-row (replicated across 4 lane-groups)
    const float zs = 0.125f * 1.44269504088896f;  // scale * log2(e)

    for (int s0 = 0; s0 < T_SEQ; s0 += 64) {
        // K tiles as A-fragments: row = k-local = qq
        bf16x8 kf[4][2];
#pragma unroll
        for (int hf = 0; hf < 4; hf++) {
            const uint16_t* kp = kbase + (size_t)(s0 + hf * 16 + qq) * C_DIM + ko;
            kf[hf][0] = *reinterpret_cast<const bf16x8*>(kp);
            kf[hf][1] = *reinterpret_cast<const bf16x8*>(kp + 32);
        }
        f32x4 sc[4];
#pragma unroll
        for (int hf = 0; hf < 4; hf++) {
            f32x4 t = {};
            t = __builtin_amdgcn_mfma_f32_16x16x32_bf16(kf[hf][0], bq0, t, 0, 0, 0);
            t = __builtin_amdgcn_mfma_f32_16x16x32_bf16(kf[hf][1], bq1, t, 0, 0, 0);
            sc[hf] = t;   // sc[hf][j] = S[s0+hf*16+r0+j][qg]
        }
        // V loads issue now; latency hides under softmax
        bf16x8 vf[4][2];
#pragma unroll
        for (int ni = 0; ni < 4; ni++) {
            const uint16_t* vp = vbase + (size_t)(ni * 16 + qq) * T_SEQ + s0 + ko;
            vf[ni][0] = *reinterpret_cast<const bf16x8*>(vp);
            vf[ni][1] = *reinterpret_cast<const bf16x8*>(vp + 32);
        }
        // log2-domain score + faithful mask (k <= q gets -1e9; fp32 rounds to exactly -1e9)
#pragma unroll
        for (int hf = 0; hf < 4; hf++)
#pragma unroll
            for (int j = 0; j < 4; j++) {
                const int k = s0 + hf * 16 + r0 + j;
                sc[hf][j] = sc[hf][j] * zs + ((k <= qg) ? -1e9f : 0.0f);
            }
        // row max: in-lane tree over 16, then xor16 + xor32
        float mh[4];
#pragma unroll
        for (int hf = 0; hf < 4; hf++)
            mh[hf] = fmaxf(fmaxf(sc[hf][0], sc[hf][1]), fmaxf(sc[hf][2], sc[hf][3]));
        float mx = fmaxf(fmaxf(mh[0], mh[1]), fmaxf(mh[2], mh[3]));
        mx = fmaxf(mx, __shfl_xor(mx, 16));
        mx = fmaxf(mx, __shfl_xor(mx, 32));
        const float mn = fmaxf(m, mx);
        const float escv = __builtin_amdgcn_exp2f(m - mn);
        m = mn;
        float rs = 0.f;
#pragma unroll
        for (int hf = 0; hf < 4; hf++)
#pragma unroll
            for (int j = 0; j < 4; j++) {
                const float p = __builtin_amdgcn_exp2f(sc[hf][j] - m);
                sc[hf][j] = p;
                rs += p;
            }
        rs += __shfl_xor(rs, 16);
        rs += __shfl_xor(rs, 32);
        l = l * escv + rs;
        // rescale O: esc for accumulator row r0+j broadcast from lane r0+j
        float eb[4];
#pragma unroll
        for (int j = 0; j < 4; j++) eb[j] = __shfl(escv, r0 + j);
#pragma unroll
        for (int ni = 0; ni < 4; ni++)
#pragma unroll
            for (int j = 0; j < 4; j++) o[ni][j] *= eb[j];
        // pack P to bf16 pairs -> LDS (lp[q][k], stride 72)
        uint32_t* lp32 = reinterpret_cast<uint32_t*>(lp);
#pragma unroll
        for (int hf = 0; hf < 4; hf++)
#pragma unroll
            for (int jp = 0; jp < 2; jp++) {
                union { __hip_bfloat162 h2; uint32_t u; } cv;
                cv.h2 = __float22bfloat162_rn(make_float2(sc[hf][2 * jp], sc[hf][2 * jp + 1]));
                lp32[qq * 36 + hf * 8 + (r0 >> 1) + jp] = cv.u;
            }
        // single-wave block: no barrier needed, lgkmcnt dependency auto-inserted
        bf16x8 pa0 = *reinterpret_cast<const bf16x8*>(&lp[qq * 72 + ko]);
        bf16x8 pa1 = *reinterpret_cast<const bf16x8*>(&lp[qq * 72 + 32 + ko]);
#pragma unroll
        for (int ni = 0; ni < 4; ni++) {
            o[ni] = __builtin_amdgcn_mfma_f32_16x16x32_bf16(pa0, vf[ni][0], o[ni], 0, 0, 0);
            o[ni] = __builtin_amdgcn_mfma_f32_16x16x32_bf16(pa1, vf[ni][1], o[ni], 0, 0, 0);
        }
    }
    // epilogue: O[q][d], row=r0+j, col d = ni*16+qq
#pragma unroll
    for (int j = 0; j < 4; j++) {
        const float rinv = 1.0f / __shfl(l, r0 + j);
        const size_t row = (size_t)(bb * T_SEQ + q0 + r0 + j);
#pragma unroll
        for (int ni = 0; ni < 4; ni++)
            Ob[row * C_DIM + h * DH + ni * 16 + qq] = f2bf(o[ni][j] * rinv);
    }
}

extern "C" void kernel_launch(void* const* d_in, const int* in_sizes, int n_in,
                              void* d_out, int out_size, void* d_ws, size_t ws_size,
                              hipStream_t stream) {
    const float* x  = (const float*)d_in[0];
    const float* Wq = (const float*)d_in[1];
    const float* bq = (const float*)d_in[2];
    const float* Wk = (const float*)d_in[3];
    const float* bk = (const float*)d_in[4];
    const float* Wv = (const float*)d_in[5];
    const float* bv = (const float*)d_in[6];
    const float* Wo = (const float*)d_in[7];
    const float* bo = (const float*)d_in[8];
    float* out = (float*)d_out;

    char* ws = (char*)d_ws;
    uint16_t* xb    = (uint16_t*)(ws);               // 8 MB
    uint16_t* wqkvt = (uint16_t*)(ws + (8u  << 20)); // 6 MB: [3072][1024] bf16
    uint16_t* wot   = (uint16_t*)(ws + (14u << 20)); // 2 MB
    uint16_t* qb    = (uint16_t*)(ws + (16u << 20)); // 8 MB
    uint16_t* kb    = (uint16_t*)(ws + (24u << 20)); // 8 MB
    uint16_t* vt    = (uint16_t*)(ws + (32u << 20)); // 8 MB
    uint16_t* ab    = qb;  // attn out aliases qb: each attn block reads only its own q region first

    k_cast<<<2048, 256, 0, stream>>>(x, xb, (4096 * 1024) / 4);
    dim3 tg(32, 32), tb(32, 8);
    k_transpose<<<tg, tb, 0, stream>>>(Wq, wqkvt);
    k_transpose<<<tg, tb, 0, stream>>>(Wk, wqkvt + (1u << 20));
    k_transpose<<<tg, tb, 0, stream>>>(Wv, wqkvt + (2u << 20));
    k_transpose<<<tg, tb, 0, stream>>>(Wo, wot);

    k_gemm_qkv<<<dim3(32, 24), 256, 0, stream>>>(xb, wqkvt, bq, bk, bv, qb, kb, vt);
    k_attn<<<4096, 64, 0, stream>>>(qb, kb, vt, ab);
    k_gemm_o<<<dim3(32, 8), 256, 0, stream>>>(ab, wot, bo, out);
}

// Round 3
// 189.466 us; speedup vs baseline: 1.1954x; 1.0244x over previous
//
#include <hip/hip_runtime.h>
#include <hip/hip_bf16.h>
#include <stdint.h>

#define T_SEQ 1024
#define C_DIM 1024
#define NH 16
#define DH 64

typedef __attribute__((ext_vector_type(8))) __bf16 bf16x8;
typedef __attribute__((ext_vector_type(4))) float f32x4;

__device__ __forceinline__ uint16_t f2bf(float f) {
    union { float f; uint32_t u; } v; v.f = f;
    uint32_t u = v.u;
    return (uint16_t)((u + 0x7FFFu + ((u >> 16) & 1u)) >> 16);
}

// ---------- cast x f32 -> bf16 (vectorized) ----------
__global__ void k_cast(const float* __restrict__ in, uint16_t* __restrict__ out, int n4) {
    int i = blockIdx.x * blockDim.x + threadIdx.x;
    int st = gridDim.x * blockDim.x;
    for (; i < n4; i += st) {
        float4 v = reinterpret_cast<const float4*>(in)[i];
        ushort4 o;
        o.x = f2bf(v.x); o.y = f2bf(v.y); o.z = f2bf(v.z); o.w = f2bf(v.w);
        reinterpret_cast<ushort4*>(out)[i] = o;
    }
}

// ---------- transpose + cast weight: W[k][n] f32 -> Wt[n][k] bf16 ----------
__global__ void k_transpose(const float* __restrict__ in, uint16_t* __restrict__ out) {
    __shared__ float tile[32][33];
    int bx = blockIdx.x * 32;  // n block
    int by = blockIdx.y * 32;  // k block
    int tx = threadIdx.x, ty = threadIdx.y;
#pragma unroll
    for (int i = 0; i < 4; i++)
        tile[ty + i * 8][tx] = in[(size_t)(by + ty + i * 8) * C_DIM + bx + tx];
    __syncthreads();
#pragma unroll
    for (int i = 0; i < 4; i++)
        out[(size_t)(bx + ty + i * 8) * C_DIM + by + tx] = f2bf(tile[tx][ty + i * 8]);
}

// ---------- fused QKV GEMM: [4096][1024] x [3072][1024]^T ----------
__global__ __launch_bounds__(256) void k_gemm_qkv(const uint16_t* __restrict__ A,
                                                  const uint16_t* __restrict__ Bt,
                                                  const float* __restrict__ bq,
                                                  const float* __restrict__ bk,
                                                  const float* __restrict__ bv,
                                                  uint16_t* __restrict__ qb,
                                                  uint16_t* __restrict__ kb,
                                                  uint16_t* __restrict__ vt) {
    __shared__ uint16_t lA[128 * 32];
    __shared__ uint16_t lB[128 * 32];
    const int bm = blockIdx.x * 128;
    const int bn = blockIdx.y * 128;
    const int tid = threadIdx.x;
    const int lane = tid & 63;
    const int w = tid >> 6;
    const int wm = (w >> 1) * 64;
    const int wn = (w & 1) * 64;
    const int srow = tid >> 2;
    const int scol = (tid & 3) * 8;

    f32x4 acc[4][4] = {};

    for (int kt = 0; kt < C_DIM; kt += 32) {
#pragma unroll
        for (int p = 0; p < 2; p++) {
            const uint16_t* ga = A + (size_t)(bm + p * 64 + srow) * C_DIM + kt + scol;
            const uint16_t* gb = Bt + (size_t)(bn + p * 64 + srow) * C_DIM + kt + scol;
            __builtin_amdgcn_global_load_lds(
                (const __attribute__((address_space(1))) void*)ga,
                (__attribute__((address_space(3))) void*)((char*)lA + p * 4096 + w * 1024),
                16, 0, 0);
            __builtin_amdgcn_global_load_lds(
                (const __attribute__((address_space(1))) void*)gb,
                (__attribute__((address_space(3))) void*)((char*)lB + p * 4096 + w * 1024),
                16, 0, 0);
        }
        __syncthreads();
        const int ko = (lane >> 4) * 8;
        const int rr = lane & 15;
        bf16x8 af[4], bfr[4];
#pragma unroll
        for (int i = 0; i < 4; i++) {
            af[i]  = *reinterpret_cast<const bf16x8*>(&lA[(wm + i * 16 + rr) * 32 + ko]);
            bfr[i] = *reinterpret_cast<const bf16x8*>(&lB[(wn + i * 16 + rr) * 32 + ko]);
        }
#pragma unroll
        for (int mi = 0; mi < 4; mi++)
#pragma unroll
            for (int ni = 0; ni < 4; ni++)
                acc[mi][ni] = __builtin_amdgcn_mfma_f32_16x16x32_bf16(af[mi], bfr[ni], acc[mi][ni], 0, 0, 0);
        __syncthreads();
    }

    const float* bias; uint16_t* outp; int coff, vmode;
    if (bn < 1024)      { bias = bq; outp = qb; coff = 0;    vmode = 0; }
    else if (bn < 2048) { bias = bk; outp = kb; coff = 1024; vmode = 0; }
    else                { bias = bv; outp = vt; coff = 2048; vmode = 1; }

    const int r0 = (lane >> 4) * 4;
    const int cc = lane & 15;
#pragma unroll
    for (int ni = 0; ni < 4; ni++) {
        const int colg = bn + wn + ni * 16 + cc;
        const int col = colg - coff;
        const float bvv = bias[col];
#pragma unroll
        for (int mi = 0; mi < 4; mi++) {
#pragma unroll
            for (int jj = 0; jj < 4; jj++) {
                const int row = bm + wm + mi * 16 + r0 + jj;
                float v = acc[mi][ni][jj] + bvv;
                if (vmode == 0) {
                    outp[(size_t)row * C_DIM + col] = f2bf(v);
                } else {
                    const int b = row >> 10, t = row & 1023;
                    const int h = col >> 6, d = col & 63;
                    outp[((size_t)((b * NH + h) * DH + d) << 10) + t] = f2bf(v);
                }
            }
        }
    }
}

// ---------- output-proj GEMM: f32 out ----------
__global__ __launch_bounds__(256) void k_gemm_o(const uint16_t* __restrict__ A,
                                                const uint16_t* __restrict__ Bt,
                                                const float* __restrict__ bias,
                                                float* __restrict__ Out) {
    __shared__ uint16_t lA[128 * 32];
    __shared__ uint16_t lB[128 * 32];
    const int bm = blockIdx.x * 128;
    const int bn = blockIdx.y * 128;
    const int tid = threadIdx.x;
    const int lane = tid & 63;
    const int w = tid >> 6;
    const int wm = (w >> 1) * 64;
    const int wn = (w & 1) * 64;
    const int srow = tid >> 2;
    const int scol = (tid & 3) * 8;

    f32x4 acc[4][4] = {};

    for (int kt = 0; kt < C_DIM; kt += 32) {
#pragma unroll
        for (int p = 0; p < 2; p++) {
            const uint16_t* ga = A + (size_t)(bm + p * 64 + srow) * C_DIM + kt + scol;
            const uint16_t* gb = Bt + (size_t)(bn + p * 64 + srow) * C_DIM + kt + scol;
            __builtin_amdgcn_global_load_lds(
                (const __attribute__((address_space(1))) void*)ga,
                (__attribute__((address_space(3))) void*)((char*)lA + p * 4096 + w * 1024),
                16, 0, 0);
            __builtin_amdgcn_global_load_lds(
                (const __attribute__((address_space(1))) void*)gb,
                (__attribute__((address_space(3))) void*)((char*)lB + p * 4096 + w * 1024),
                16, 0, 0);
        }
        __syncthreads();
        const int ko = (lane >> 4) * 8;
        const int rr = lane & 15;
        bf16x8 af[4], bfr[4];
#pragma unroll
        for (int i = 0; i < 4; i++) {
            af[i]  = *reinterpret_cast<const bf16x8*>(&lA[(wm + i * 16 + rr) * 32 + ko]);
            bfr[i] = *reinterpret_cast<const bf16x8*>(&lB[(wn + i * 16 + rr) * 32 + ko]);
        }
#pragma unroll
        for (int mi = 0; mi < 4; mi++)
#pragma unroll
            for (int ni = 0; ni < 4; ni++)
                acc[mi][ni] = __builtin_amdgcn_mfma_f32_16x16x32_bf16(af[mi], bfr[ni], acc[mi][ni], 0, 0, 0);
        __syncthreads();
    }

    const int r0 = (lane >> 4) * 4;
    const int cc = lane & 15;
#pragma unroll
    for (int ni = 0; ni < 4; ni++) {
        const int col = bn + wn + ni * 16 + cc;
        const float bvv = bias[col];
#pragma unroll
        for (int mi = 0; mi < 4; mi++)
#pragma unroll
            for (int jj = 0; jj < 4; jj++) {
                const int row = bm + wm + mi * 16 + r0 + jj;
                Out[(size_t)row * C_DIM + col] = acc[mi][ni][jj] + bvv;
            }
    }
}

// ---------- flash attention: 4-wave blocks, KV split-K, masked-tile skip ----------
// Block = one (b,h,q-tile of 16 rows). Wave w handles KV tiles {w,w+4,w+8,w+12} (64 cols each).
// Partial (m,l,o) merged via LDS. Tiles with s0+63<=q0 contribute exactly 0 -> skipped
// (except q0==1008, where row 1023 is fully masked and needs the uniform path).
__global__ __launch_bounds__(256, 8) void k_attn(const uint16_t* __restrict__ Q,
                                                 const uint16_t* __restrict__ Kb,
                                                 const uint16_t* __restrict__ Vt,
                                                 uint16_t* __restrict__ Ob) {
    __shared__ float smem[4608];                 // 18432 B: merge buf; P tiles union'd on top
    const int tid = threadIdx.x;
    const int lane = tid & 63;
    const int w = tid >> 6;
    uint16_t* lp = reinterpret_cast<uint16_t*>(smem) + w * 1152;  // 16*72 per wave

    // XCD-aware bijective swizzle: 8 heads' K/V (2MB) pinned per XCD L2
    const int id = blockIdx.x;
    const int sw = (id & 7) * 512 + (id >> 3);
    const int q0 = (sw & 63) * 16;
    const int bh = sw >> 6;
    const int bb = bh >> 4, h = bh & 15;
    const int qq = lane & 15;
    const int g  = lane >> 4;
    const int ko = g * 8;
    const int r0 = g * 4;
    const int qg = q0 + qq;

    const uint16_t* qp = Q + (size_t)(bb * T_SEQ + qg) * C_DIM + h * DH + ko;
    bf16x8 bq0 = *reinterpret_cast<const bf16x8*>(qp);
    bf16x8 bq1 = *reinterpret_cast<const bf16x8*>(qp + 32);

    const uint16_t* kbase = Kb + (size_t)(bb * T_SEQ) * C_DIM + h * DH;
    const uint16_t* vbase = Vt + (size_t)bh * DH * T_SEQ;

    f32x4 o[4] = {};
    float m = -INFINITY, l = 0.f;
    const float zs = 0.125f * 1.44269504088896f;

#pragma unroll
    for (int t = 0; t < 4; t++) {
        const int s0 = (w + t * 4) << 6;
        if (q0 != 1008 && s0 + 63 <= q0) continue;  // exactly-zero tile (wave-uniform branch)

        bf16x8 kf[4][2];
#pragma unroll
        for (int hf = 0; hf < 4; hf++) {
            const uint16_t* kp = kbase + (size_t)(s0 + hf * 16 + qq) * C_DIM + ko;
            kf[hf][0] = *reinterpret_cast<const bf16x8*>(kp);
            kf[hf][1] = *reinterpret_cast<const bf16x8*>(kp + 32);
        }
        f32x4 sc[4];
#pragma unroll
        for (int hf = 0; hf < 4; hf++) {
            f32x4 tt = {};
            tt = __builtin_amdgcn_mfma_f32_16x16x32_bf16(kf[hf][0], bq0, tt, 0, 0, 0);
            tt = __builtin_amdgcn_mfma_f32_16x16x32_bf16(kf[hf][1], bq1, tt, 0, 0, 0);
            sc[hf] = tt;
        }
        bf16x8 vf[4][2];
#pragma unroll
        for (int ni = 0; ni < 4; ni++) {
            const uint16_t* vp = vbase + (size_t)(ni * 16 + qq) * T_SEQ + s0 + ko;
            vf[ni][0] = *reinterpret_cast<const bf16x8*>(vp);
            vf[ni][1] = *reinterpret_cast<const bf16x8*>(vp + 32);
        }
#pragma unroll
        for (int hf = 0; hf < 4; hf++)
#pragma unroll
            for (int j = 0; j < 4; j++) {
                const int k = s0 + hf * 16 + r0 + j;
                sc[hf][j] = sc[hf][j] * zs + ((k <= qg) ? -1e9f : 0.0f);
            }
        float mh[4];
#pragma unroll
        for (int hf = 0; hf < 4; hf++)
            mh[hf] = fmaxf(fmaxf(sc[hf][0], sc[hf][1]), fmaxf(sc[hf][2], sc[hf][3]));
        float mx = fmaxf(fmaxf(mh[0], mh[1]), fmaxf(mh[2], mh[3]));
        mx = fmaxf(mx, __shfl_xor(mx, 16));
        mx = fmaxf(mx, __shfl_xor(mx, 32));
        const float mn = fmaxf(m, mx);
        const float escv = __builtin_amdgcn_exp2f(m - mn);
        m = mn;
        float rs = 0.f;
#pragma unroll
        for (int hf = 0; hf < 4; hf++)
#pragma unroll
            for (int j = 0; j < 4; j++) {
                const float p = __builtin_amdgcn_exp2f(sc[hf][j] - m);
                sc[hf][j] = p;
                rs += p;
            }
        rs += __shfl_xor(rs, 16);
        rs += __shfl_xor(rs, 32);
        l = l * escv + rs;
        float eb[4];
#pragma unroll
        for (int j = 0; j < 4; j++) eb[j] = __shfl(escv, r0 + j);
#pragma unroll
        for (int ni = 0; ni < 4; ni++)
#pragma unroll
            for (int j = 0; j < 4; j++) o[ni][j] *= eb[j];
        // pack P -> LDS (lp[q][k], stride 72)
        uint32_t* lp32 = reinterpret_cast<uint32_t*>(lp);
#pragma unroll
        for (int hf = 0; hf < 4; hf++)
#pragma unroll
            for (int jp = 0; jp < 2; jp++) {
                union { __hip_bfloat162 h2; uint32_t u; } cv;
                cv.h2 = __float22bfloat162_rn(make_float2(sc[hf][2 * jp], sc[hf][2 * jp + 1]));
                lp32[qq * 36 + hf * 8 + (r0 >> 1) + jp] = cv.u;
            }
        bf16x8 pa0 = *reinterpret_cast<const bf16x8*>(&lp[qq * 72 + ko]);
        bf16x8 pa1 = *reinterpret_cast<const bf16x8*>(&lp[qq * 72 + 32 + ko]);
#pragma unroll
        for (int ni = 0; ni < 4; ni++) {
            o[ni] = __builtin_amdgcn_mfma_f32_16x16x32_bf16(pa0, vf[ni][0], o[ni], 0, 0, 0);
            o[ni] = __builtin_amdgcn_mfma_f32_16x16x32_bf16(pa1, vf[ni][1], o[ni], 0, 0, 0);
        }
    }

    // ---- split-K merge via LDS ----
    __syncthreads();   // all waves done with P tiles (smem reuse)
    {
        float* mbw = smem + (size_t)(w * 64 + lane) * 18;
#pragma unroll
        for (int ni = 0; ni < 4; ni++)
#pragma unroll
            for (int j = 0; j < 4; j++) mbw[ni * 4 + j] = o[ni][j];
        mbw[16] = m;
        mbw[17] = l;
    }
    __syncthreads();
    // wave w merges + writes output columns [16w, 16w+16)
#pragma unroll
    for (int j = 0; j < 4; j++) {
        const int row = r0 + j;
        float mg = -INFINITY;
#pragma unroll
        for (int w2 = 0; w2 < 4; w2++)
            mg = fmaxf(mg, smem[(size_t)(w2 * 64 + row) * 18 + 16]);
        float L = 0.f, og = 0.f;
#pragma unroll
        for (int w2 = 0; w2 < 4; w2++) {
            const float mw = smem[(size_t)(w2 * 64 + row) * 18 + 16];
            const float e = __builtin_amdgcn_exp2f(mw - mg);
            L  += smem[(size_t)(w2 * 64 + row) * 18 + 17] * e;
            og += smem[(size_t)(w2 * 64 + lane) * 18 + w * 4 + j] * e;
        }
        Ob[(size_t)(bb * T_SEQ + q0 + row) * C_DIM + h * DH + w * 16 + qq] = f2bf(og / L);
    }
}

extern "C" void kernel_launch(void* const* d_in, const int* in_sizes, int n_in,
                              void* d_out, int out_size, void* d_ws, size_t ws_size,
                              hipStream_t stream) {
    const float* x  = (const float*)d_in[0];
    const float* Wq = (const float*)d_in[1];
    const float* bq = (const float*)d_in[2];
    const float* Wk = (const float*)d_in[3];
    const float* bk = (const float*)d_in[4];
    const float* Wv = (const float*)d_in[5];
    const float* bv = (const float*)d_in[6];
    const float* Wo = (const float*)d_in[7];
    const float* bo = (const float*)d_in[8];
    float* out = (float*)d_out;

    char* ws = (char*)d_ws;
    uint16_t* xb    = (uint16_t*)(ws);               // 8 MB
    uint16_t* wqkvt = (uint16_t*)(ws + (8u  << 20)); // 6 MB: [3072][1024] bf16
    uint16_t* wot   = (uint16_t*)(ws + (14u << 20)); // 2 MB
    uint16_t* qb    = (uint16_t*)(ws + (16u << 20)); // 8 MB
    uint16_t* kb    = (uint16_t*)(ws + (24u << 20)); // 8 MB
    uint16_t* vt    = (uint16_t*)(ws + (32u << 20)); // 8 MB
    uint16_t* ab    = qb;  // attn out aliases qb: blocks read their own q rows before writing them

    k_cast<<<2048, 256, 0, stream>>>(x, xb, (4096 * 1024) / 4);
    dim3 tg(32, 32), tb(32, 8);
    k_transpose<<<tg, tb, 0, stream>>>(Wq, wqkvt);
    k_transpose<<<tg, tb, 0, stream>>>(Wk, wqkvt + (1u << 20));
    k_transpose<<<tg, tb, 0, stream>>>(Wv, wqkvt + (2u << 20));
    k_transpose<<<tg, tb, 0, stream>>>(Wo, wot);

    k_gemm_qkv<<<dim3(32, 24), 256, 0, stream>>>(xb, wqkvt, bq, bk, bv, qb, kb, vt);
    k_attn<<<4096, 256, 0, stream>>>(qb, kb, vt, ab);
    k_gemm_o<<<dim3(32, 8), 256, 0, stream>>>(ab, wot, bo, out);
}

// Round 4
// 143.925 us; speedup vs baseline: 1.5737x; 1.3164x over previous
//
#include <hip/hip_runtime.h>
#include <hip/hip_bf16.h>
#include <stdint.h>

#define T_SEQ 1024
#define C_DIM 1024
#define NH 16
#define DH 64

typedef __attribute__((ext_vector_type(8))) __bf16 bf16x8;
typedef __attribute__((ext_vector_type(4))) float f32x4;

__device__ __forceinline__ uint16_t f2bf(float f) {
    union { float f; uint32_t u; } v; v.f = f;
    uint32_t u = v.u;
    return (uint16_t)((u + 0x7FFFu + ((u >> 16) & 1u)) >> 16);
}

// ---------- cast x f32 -> bf16 (vectorized) ----------
__global__ void k_cast(const float* __restrict__ in, uint16_t* __restrict__ out, int n4) {
    int i = blockIdx.x * blockDim.x + threadIdx.x;
    int st = gridDim.x * blockDim.x;
    for (; i < n4; i += st) {
        float4 v = reinterpret_cast<const float4*>(in)[i];
        ushort4 o;
        o.x = f2bf(v.x); o.y = f2bf(v.y); o.z = f2bf(v.z); o.w = f2bf(v.w);
        reinterpret_cast<ushort4*>(out)[i] = o;
    }
}

// ---------- transpose + cast weight: W[k][n] f32 -> Wt[n][k] bf16 ----------
__global__ void k_transpose(const float* __restrict__ in, uint16_t* __restrict__ out) {
    __shared__ float tile[32][33];
    int bx = blockIdx.x * 32;  // n block
    int by = blockIdx.y * 32;  // k block
    int tx = threadIdx.x, ty = threadIdx.y;
#pragma unroll
    for (int i = 0; i < 4; i++)
        tile[ty + i * 8][tx] = in[(size_t)(by + ty + i * 8) * C_DIM + bx + tx];
    __syncthreads();
#pragma unroll
    for (int i = 0; i < 4; i++)
        out[(size_t)(bx + ty + i * 8) * C_DIM + by + tx] = f2bf(tile[tx][ty + i * 8]);
}

// ---------- fused QKV GEMM: [4096][1024] x [3072][1024]^T ----------
__global__ __launch_bounds__(256) void k_gemm_qkv(const uint16_t* __restrict__ A,
                                                  const uint16_t* __restrict__ Bt,
                                                  const float* __restrict__ bq,
                                                  const float* __restrict__ bk,
                                                  const float* __restrict__ bv,
                                                  uint16_t* __restrict__ qb,
                                                  uint16_t* __restrict__ kb,
                                                  uint16_t* __restrict__ vt) {
    __shared__ uint16_t lA[128 * 32];
    __shared__ uint16_t lB[128 * 32];
    const int bm = blockIdx.x * 128;
    const int bn = blockIdx.y * 128;
    const int tid = threadIdx.x;
    const int lane = tid & 63;
    const int w = tid >> 6;
    const int wm = (w >> 1) * 64;
    const int wn = (w & 1) * 64;
    const int srow = tid >> 2;
    const int scol = (tid & 3) * 8;

    f32x4 acc[4][4] = {};

    for (int kt = 0; kt < C_DIM; kt += 32) {
#pragma unroll
        for (int p = 0; p < 2; p++) {
            const uint16_t* ga = A + (size_t)(bm + p * 64 + srow) * C_DIM + kt + scol;
            const uint16_t* gb = Bt + (size_t)(bn + p * 64 + srow) * C_DIM + kt + scol;
            __builtin_amdgcn_global_load_lds(
                (const __attribute__((address_space(1))) void*)ga,
                (__attribute__((address_space(3))) void*)((char*)lA + p * 4096 + w * 1024),
                16, 0, 0);
            __builtin_amdgcn_global_load_lds(
                (const __attribute__((address_space(1))) void*)gb,
                (__attribute__((address_space(3))) void*)((char*)lB + p * 4096 + w * 1024),
                16, 0, 0);
        }
        __syncthreads();
        const int ko = (lane >> 4) * 8;
        const int rr = lane & 15;
        bf16x8 af[4], bfr[4];
#pragma unroll
        for (int i = 0; i < 4; i++) {
            af[i]  = *reinterpret_cast<const bf16x8*>(&lA[(wm + i * 16 + rr) * 32 + ko]);
            bfr[i] = *reinterpret_cast<const bf16x8*>(&lB[(wn + i * 16 + rr) * 32 + ko]);
        }
#pragma unroll
        for (int mi = 0; mi < 4; mi++)
#pragma unroll
            for (int ni = 0; ni < 4; ni++)
                acc[mi][ni] = __builtin_amdgcn_mfma_f32_16x16x32_bf16(af[mi], bfr[ni], acc[mi][ni], 0, 0, 0);
        __syncthreads();
    }

    const float* bias; uint16_t* outp; int coff, vmode;
    if (bn < 1024)      { bias = bq; outp = qb; coff = 0;    vmode = 0; }
    else if (bn < 2048) { bias = bk; outp = kb; coff = 1024; vmode = 0; }
    else                { bias = bv; outp = vt; coff = 2048; vmode = 1; }

    const int r0 = (lane >> 4) * 4;
    const int cc = lane & 15;
#pragma unroll
    for (int ni = 0; ni < 4; ni++) {
        const int colg = bn + wn + ni * 16 + cc;
        const int col = colg - coff;
        const float bvv = bias[col];
#pragma unroll
        for (int mi = 0; mi < 4; mi++) {
#pragma unroll
            for (int jj = 0; jj < 4; jj++) {
                const int row = bm + wm + mi * 16 + r0 + jj;
                float v = acc[mi][ni][jj] + bvv;
                if (vmode == 0) {
                    outp[(size_t)row * C_DIM + col] = f2bf(v);
                } else {
                    const int b = row >> 10, t = row & 1023;
                    const int h = col >> 6, d = col & 63;
                    outp[((size_t)((b * NH + h) * DH + d) << 10) + t] = f2bf(v);
                }
            }
        }
    }
}

// ---------- output-proj GEMM: f32 out ----------
__global__ __launch_bounds__(256) void k_gemm_o(const uint16_t* __restrict__ A,
                                                const uint16_t* __restrict__ Bt,
                                                const float* __restrict__ bias,
                                                float* __restrict__ Out) {
    __shared__ uint16_t lA[128 * 32];
    __shared__ uint16_t lB[128 * 32];
    const int bm = blockIdx.x * 128;
    const int bn = blockIdx.y * 128;
    const int tid = threadIdx.x;
    const int lane = tid & 63;
    const int w = tid >> 6;
    const int wm = (w >> 1) * 64;
    const int wn = (w & 1) * 64;
    const int srow = tid >> 2;
    const int scol = (tid & 3) * 8;

    f32x4 acc[4][4] = {};

    for (int kt = 0; kt < C_DIM; kt += 32) {
#pragma unroll
        for (int p = 0; p < 2; p++) {
            const uint16_t* ga = A + (size_t)(bm + p * 64 + srow) * C_DIM + kt + scol;
            const uint16_t* gb = Bt + (size_t)(bn + p * 64 + srow) * C_DIM + kt + scol;
            __builtin_amdgcn_global_load_lds(
                (const __attribute__((address_space(1))) void*)ga,
                (__attribute__((address_space(3))) void*)((char*)lA + p * 4096 + w * 1024),
                16, 0, 0);
            __builtin_amdgcn_global_load_lds(
                (const __attribute__((address_space(1))) void*)gb,
                (__attribute__((address_space(3))) void*)((char*)lB + p * 4096 + w * 1024),
                16, 0, 0);
        }
        __syncthreads();
        const int ko = (lane >> 4) * 8;
        const int rr = lane & 15;
        bf16x8 af[4], bfr[4];
#pragma unroll
        for (int i = 0; i < 4; i++) {
            af[i]  = *reinterpret_cast<const bf16x8*>(&lA[(wm + i * 16 + rr) * 32 + ko]);
            bfr[i] = *reinterpret_cast<const bf16x8*>(&lB[(wn + i * 16 + rr) * 32 + ko]);
        }
#pragma unroll
        for (int mi = 0; mi < 4; mi++)
#pragma unroll
            for (int ni = 0; ni < 4; ni++)
                acc[mi][ni] = __builtin_amdgcn_mfma_f32_16x16x32_bf16(af[mi], bfr[ni], acc[mi][ni], 0, 0, 0);
        __syncthreads();
    }

    const int r0 = (lane >> 4) * 4;
    const int cc = lane & 15;
#pragma unroll
    for (int ni = 0; ni < 4; ni++) {
        const int col = bn + wn + ni * 16 + cc;
        const float bvv = bias[col];
#pragma unroll
        for (int mi = 0; mi < 4; mi++)
#pragma unroll
            for (int jj = 0; jj < 4; jj++) {
                const int row = bm + wm + mi * 16 + r0 + jj;
                Out[(size_t)row * C_DIM + col] = acc[mi][ni][jj] + bvv;
            }
    }
}

// Stage one 64x64 bf16 K tile (8KB) into LDS, linear dest + inverse-swizzled source.
// Swizzle: byte-in-row cb holds source cb ^ ((row&7)<<4). Read applies same XOR.
__device__ __forceinline__ void stage_k(const uint16_t* kbase, int s0, char* buf, int tid) {
    const int w = tid >> 6;
    const int cb = (((tid & 7) ^ ((tid >> 3) & 7)) << 4);
#pragma unroll
    for (int i = 0; i < 2; i++) {
        const int r = i * 32 + (tid >> 3);
        const uint16_t* src = kbase + (size_t)(s0 + r) * C_DIM + (cb >> 1);
        __builtin_amdgcn_global_load_lds(
            (const __attribute__((address_space(1))) void*)src,
            (__attribute__((address_space(3))) void*)(buf + i * 4096 + w * 1024),
            16, 0, 0);
    }
}

// ---------- flash attention: 4-wave block, 64 q-rows, LDS-staged K (dbuf+swizzle) ----------
// wave w owns q-rows [q0+16w, q0+16w+16). K tile shared via LDS; V direct global->reg.
__global__ __launch_bounds__(256, 4) void k_attn(const uint16_t* __restrict__ Q,
                                                 const uint16_t* __restrict__ Kb,
                                                 const uint16_t* __restrict__ Vt,
                                                 uint16_t* __restrict__ Ob) {
    __shared__ char smem[16384 + 4 * 2304];  // K dbuf 2x8KB + P 4x(16x72x2B)
    const int tid = threadIdx.x;
    const int lane = tid & 63;
    const int w = tid >> 6;
    uint16_t* lp = reinterpret_cast<uint16_t*>(smem + 16384 + w * 2304);

    // XCD swizzle (bijective, 1024%8==0): 8 heads per XCD; zigzag qblk for load balance
    const int id = blockIdx.x;
    const int sw = (id & 7) * 128 + (id >> 3);
    const int bh = sw >> 4;
    const int jj = sw & 15;
    const int qblk = (jj & 1) ? (15 - (jj >> 1)) : (jj >> 1);
    const int q0 = qblk * 64;
    const int bb = bh >> 4, h = bh & 15;
    const int qq = lane & 15;
    const int g  = lane >> 4;
    const int ko = g * 8;
    const int r0 = g * 4;
    const int qg = q0 + w * 16 + qq;

    const uint16_t* qp = Q + (size_t)(bb * T_SEQ + qg) * C_DIM + h * DH + ko;
    bf16x8 bq0 = *reinterpret_cast<const bf16x8*>(qp);
    bf16x8 bq1 = *reinterpret_cast<const bf16x8*>(qp + 32);

    const uint16_t* kbase = Kb + (size_t)bb * T_SEQ * C_DIM + h * DH;
    const uint16_t* vbase = Vt + (size_t)bh * DH * T_SEQ;

    f32x4 o[4] = {};
    float m = -INFINITY, l = 0.f;
    const float zs = 0.125f * 1.44269504088896f;

    // tiles with s0+63 <= q0 are exactly zero for all rows in block; q0==960 keeps all
    // (row 1023 fully masked -> uniform path; junk from masked tiles wiped by esc=0)
    const int t0 = (q0 == 960) ? 0 : qblk;
    stage_k(kbase, t0 * 64, smem, tid);

    const int swz0 = ((g * 16) ^ ((qq & 7) << 4)) >> 1;        // elem off, cols 0-31
    const int swz1 = ((64 + g * 16) ^ ((qq & 7) << 4)) >> 1;   // elem off, cols 32-63

    for (int t = t0; t < 16; t++) {
        const int cur = (t - t0) & 1;
        __syncthreads();   // K(t) landed; buf[cur^1] free; vmcnt drained
        if (t < 15) stage_k(kbase, (t + 1) * 64, smem + (cur ^ 1) * 8192, tid);
        const int s0 = t * 64;

        // V direct loads, issued early; latency hides under QK+softmax
        bf16x8 vf[4][2];
#pragma unroll
        for (int ni = 0; ni < 4; ni++) {
            const uint16_t* vp = vbase + (size_t)(ni * 16 + qq) * T_SEQ + s0 + ko;
            vf[ni][0] = *reinterpret_cast<const bf16x8*>(vp);
            vf[ni][1] = *reinterpret_cast<const bf16x8*>(vp + 32);
        }

        const uint16_t* kb_cur = reinterpret_cast<const uint16_t*>(smem + cur * 8192);
        f32x4 sc[4];
#pragma unroll
        for (int hf = 0; hf < 4; hf++) {
            const int rb = (hf * 16 + qq) * 64;
            bf16x8 k0 = *reinterpret_cast<const bf16x8*>(&kb_cur[rb + swz0]);
            bf16x8 k1 = *reinterpret_cast<const bf16x8*>(&kb_cur[rb + swz1]);
            f32x4 tt = {};
            tt = __builtin_amdgcn_mfma_f32_16x16x32_bf16(k0, bq0, tt, 0, 0, 0);
            tt = __builtin_amdgcn_mfma_f32_16x16x32_bf16(k1, bq1, tt, 0, 0, 0);
            sc[hf] = tt;   // sc[hf][j] = S[k=s0+hf*16+r0+j][q=qg]
        }
        // log2-domain + faithful mask (fp32 rounds masked to exactly -1e9)
#pragma unroll
        for (int hf = 0; hf < 4; hf++)
#pragma unroll
            for (int j = 0; j < 4; j++) {
                const int k = s0 + hf * 16 + r0 + j;
                sc[hf][j] = sc[hf][j] * zs + ((k <= qg) ? -1e9f : 0.0f);
            }
        float mh[4];
#pragma unroll
        for (int hf = 0; hf < 4; hf++)
            mh[hf] = fmaxf(fmaxf(sc[hf][0], sc[hf][1]), fmaxf(sc[hf][2], sc[hf][3]));
        float mx = fmaxf(fmaxf(mh[0], mh[1]), fmaxf(mh[2], mh[3]));
        mx = fmaxf(mx, __shfl_xor(mx, 16));
        mx = fmaxf(mx, __shfl_xor(mx, 32));
        const float mn = fmaxf(m, mx);
        const float escv = __builtin_amdgcn_exp2f(m - mn);
        m = mn;
        float rs = 0.f;
#pragma unroll
        for (int hf = 0; hf < 4; hf++)
#pragma unroll
            for (int j = 0; j < 4; j++) {
                const float p = __builtin_amdgcn_exp2f(sc[hf][j] - m);
                sc[hf][j] = p;
                rs += p;
            }
        rs += __shfl_xor(rs, 16);
        rs += __shfl_xor(rs, 32);
        l = l * escv + rs;
        float eb[4];
#pragma unroll
        for (int j = 0; j < 4; j++) eb[j] = __shfl(escv, r0 + j);
#pragma unroll
        for (int ni = 0; ni < 4; ni++)
#pragma unroll
            for (int j = 0; j < 4; j++) o[ni][j] *= eb[j];
        // pack P -> per-wave LDS (lp[q][k], stride 72) — wave-private, lgkmcnt-ordered
        uint32_t* lp32 = reinterpret_cast<uint32_t*>(lp);
#pragma unroll
        for (int hf = 0; hf < 4; hf++)
#pragma unroll
            for (int jp = 0; jp < 2; jp++) {
                union { __hip_bfloat162 h2; uint32_t u; } cv;
                cv.h2 = __float22bfloat162_rn(make_float2(sc[hf][2 * jp], sc[hf][2 * jp + 1]));
                lp32[qq * 36 + hf * 8 + (r0 >> 1) + jp] = cv.u;
            }
        bf16x8 pa0 = *reinterpret_cast<const bf16x8*>(&lp[qq * 72 + ko]);
        bf16x8 pa1 = *reinterpret_cast<const bf16x8*>(&lp[qq * 72 + 32 + ko]);
#pragma unroll
        for (int ni = 0; ni < 4; ni++) {
            o[ni] = __builtin_amdgcn_mfma_f32_16x16x32_bf16(pa0, vf[ni][0], o[ni], 0, 0, 0);
            o[ni] = __builtin_amdgcn_mfma_f32_16x16x32_bf16(pa1, vf[ni][1], o[ni], 0, 0, 0);
        }
    }
    // epilogue
#pragma unroll
    for (int j = 0; j < 4; j++) {
        const float rinv = 1.0f / __shfl(l, r0 + j);
        const size_t row = (size_t)(bb * T_SEQ + q0 + w * 16 + r0 + j);
#pragma unroll
        for (int ni = 0; ni < 4; ni++)
            Ob[row * C_DIM + h * DH + ni * 16 + qq] = f2bf(o[ni][j] * rinv);
    }
}

extern "C" void kernel_launch(void* const* d_in, const int* in_sizes, int n_in,
                              void* d_out, int out_size, void* d_ws, size_t ws_size,
                              hipStream_t stream) {
    const float* x  = (const float*)d_in[0];
    const float* Wq = (const float*)d_in[1];
    const float* bq = (const float*)d_in[2];
    const float* Wk = (const float*)d_in[3];
    const float* bk = (const float*)d_in[4];
    const float* Wv = (const float*)d_in[5];
    const float* bv = (const float*)d_in[6];
    const float* Wo = (const float*)d_in[7];
    const float* bo = (const float*)d_in[8];
    float* out = (float*)d_out;

    char* ws = (char*)d_ws;
    uint16_t* xb    = (uint16_t*)(ws);               // 8 MB
    uint16_t* wqkvt = (uint16_t*)(ws + (8u  << 20)); // 6 MB: [3072][1024] bf16
    uint16_t* wot   = (uint16_t*)(ws + (14u << 20)); // 2 MB
    uint16_t* qb    = (uint16_t*)(ws + (16u << 20)); // 8 MB
    uint16_t* kb    = (uint16_t*)(ws + (24u << 20)); // 8 MB
    uint16_t* vt    = (uint16_t*)(ws + (32u << 20)); // 8 MB
    uint16_t* ab    = qb;  // attn out aliases qb: blocks read their own q rows before writing them

    k_cast<<<2048, 256, 0, stream>>>(x, xb, (4096 * 1024) / 4);
    dim3 tg(32, 32), tb(32, 8);
    k_transpose<<<tg, tb, 0, stream>>>(Wq, wqkvt);
    k_transpose<<<tg, tb, 0, stream>>>(Wk, wqkvt + (1u << 20));
    k_transpose<<<tg, tb, 0, stream>>>(Wv, wqkvt + (2u << 20));
    k_transpose<<<tg, tb, 0, stream>>>(Wo, wot);

    k_gemm_qkv<<<dim3(32, 24), 256, 0, stream>>>(xb, wqkvt, bq, bk, bv, qb, kb, vt);
    k_attn<<<1024, 256, 0, stream>>>(qb, kb, vt, ab);
    k_gemm_o<<<dim3(32, 8), 256, 0, stream>>>(ab, wot, bo, out);
}